// Round 8
// baseline (143.298 us; speedup 1.0000x reference)
//
#include <hip/hip_runtime.h>
#include <hip/hip_bf16.h>
#include <math.h>
#include <stdint.h>

#define N_NODES 100000
#define N_EDGES 1600000
#define IN_DIM 256
#define OUT_DIM 64

#define NCB   98                         // coarse buckets: dst>>10 (98*1024 >= 100000)
#define CWIN  1024                       // nodes per coarse bucket
#define NPART 256                        // edge partitions; 256 * 6250 = 1.6M exact
#define EPP   (N_EDGES / NPART)          // 6250
#define SCAN_N (NCB * NPART)             // 25088
#define SCAN_PER 25                      // ceil(25088/1024)

typedef __attribute__((ext_vector_type(8))) short bh8;   // 8 x bf16 frag
typedef __attribute__((ext_vector_type(4))) float f4;    // mfma accumulator

// f32 -> bf16 round-to-nearest-even
static __device__ __forceinline__ unsigned short f2bf(float f) {
    unsigned u = __float_as_uint(f);
    unsigned r = (u + 0x7FFFu + ((u >> 16) & 1u)) >> 16;
    return (unsigned short)r;
}

// ---------------------------------------------------------------------------
// Kernel A (MFMA): Wh_bf16 = bf16(h) @ bf16(W).T + fused p_src/p_dst.
// (unchanged — W resident in LDS, h global->reg, no K-loop barriers)
// ---------------------------------------------------------------------------
__global__ __launch_bounds__(256) void gat_gemm(
    const float* __restrict__ h, const float* __restrict__ W,
    const float* __restrict__ a, unsigned short* __restrict__ WhB,
    float* __restrict__ p_src, float* __restrict__ p_dst)
{
    __shared__ __align__(16) unsigned short Wlds[64 * 256];   // 32 KB

    const int t = threadIdx.x;
    const int lane = t & 63;
    const int wv = t >> 6;
    const int cl = lane & 15;
    const int g  = lane >> 4;

    {
        const int c = t >> 2;
        const int kb = (t & 3) * 8;
        #pragma unroll
        for (int it = 0; it < 8; ++it) {
            const int k16 = kb + it;
            const float4 lo = *(const float4*)(W + c * IN_DIM + k16 * 8);
            const float4 hi = *(const float4*)(W + c * IN_DIM + k16 * 8 + 4);
            unsigned short tmp[8];
            tmp[0] = f2bf(lo.x); tmp[1] = f2bf(lo.y);
            tmp[2] = f2bf(lo.z); tmp[3] = f2bf(lo.w);
            tmp[4] = f2bf(hi.x); tmp[5] = f2bf(hi.y);
            tmp[6] = f2bf(hi.z); tmp[7] = f2bf(hi.w);
            const int chunk = c * 32 + (k16 ^ (c & 7));     // XOR swizzle
            *(uint4*)&Wlds[chunk * 8] = *(uint4*)tmp;
        }
    }
    __syncthreads();

    const int node0 = blockIdx.x * 128 + wv * 32;

    float aS[4], aD[4];
    #pragma unroll
    for (int nt = 0; nt < 4; ++nt) {
        aS[nt] = a[nt * 16 + cl];
        aD[nt] = a[OUT_DIM + nt * 16 + cl];
    }

    f4 acc[2][4];
    #pragma unroll
    for (int mt = 0; mt < 2; ++mt)
        #pragma unroll
        for (int nt = 0; nt < 4; ++nt) acc[mt][nt] = (f4){0.f, 0.f, 0.f, 0.f};

    for (int ks = 0; ks < 8; ++ks) {
        bh8 bf[4];
        #pragma unroll
        for (int nt = 0; nt < 4; ++nt) {
            const int col = nt * 16 + cl;
            const int k16 = ks * 4 + g;
            const int chunk = col * 32 + (k16 ^ (col & 7));
            bf[nt] = *(const bh8*)&Wlds[chunk * 8];
        }
        #pragma unroll
        for (int mt = 0; mt < 2; ++mt) {
            int row = node0 + mt * 16 + cl;
            row = (row < N_NODES) ? row : N_NODES - 1;
            const float* hp = h + (size_t)row * IN_DIM + ks * 32 + g * 8;
            const float4 lo = *(const float4*)hp;
            const float4 hi = *(const float4*)(hp + 4);
            bh8 af;
            af[0] = (short)f2bf(lo.x); af[1] = (short)f2bf(lo.y);
            af[2] = (short)f2bf(lo.z); af[3] = (short)f2bf(lo.w);
            af[4] = (short)f2bf(hi.x); af[5] = (short)f2bf(hi.y);
            af[6] = (short)f2bf(hi.z); af[7] = (short)f2bf(hi.w);
            #pragma unroll
            for (int nt = 0; nt < 4; ++nt)
                acc[mt][nt] = __builtin_amdgcn_mfma_f32_16x16x32_bf16(
                    af, bf[nt], acc[mt][nt], 0, 0, 0);
        }
    }

    #pragma unroll
    for (int mt = 0; mt < 2; ++mt) {
        #pragma unroll
        for (int r = 0; r < 4; ++r) {
            const int row = node0 + mt * 16 + g * 4 + r;
            float ps = 0.f, pd = 0.f;
            #pragma unroll
            for (int nt = 0; nt < 4; ++nt) {
                ps = fmaf(acc[mt][nt][r], aS[nt], ps);
                pd = fmaf(acc[mt][nt][r], aD[nt], pd);
            }
            #pragma unroll
            for (int o = 8; o > 0; o >>= 1) {
                ps += __shfl_xor(ps, o);
                pd += __shfl_xor(pd, o);
            }
            if (row < N_NODES) {
                #pragma unroll
                for (int nt = 0; nt < 4; ++nt)
                    WhB[(size_t)row * OUT_DIM + nt * 16 + cl] =
                        f2bf(acc[mt][nt][r]);
                if (cl == 0) { p_src[row] = ps; p_dst[row] = pd; }
            }
        }
    }
}

// ---------------------------------------------------------------------------
// Coarse histogram: cntA[coarse_bucket][partition], LDS-combined.
// ---------------------------------------------------------------------------
__global__ __launch_bounds__(256) void gat_hist_coarse(
    const int* __restrict__ dst, int* __restrict__ cur2dA)
{
    __shared__ int lh[NCB];
    if (threadIdx.x < NCB) lh[threadIdx.x] = 0;
    __syncthreads();
    const int e0 = blockIdx.x * EPP;
    for (int e = e0 + threadIdx.x; e < e0 + EPP; e += 256)
        atomicAdd(&lh[dst[e] >> 10], 1);
    __syncthreads();
    if (threadIdx.x < NCB)
        cur2dA[threadIdx.x * NPART + blockIdx.x] = lh[threadIdx.x];
}

// ---------------------------------------------------------------------------
// Single-block exclusive scan over cur2dA[25088], in place.
// ---------------------------------------------------------------------------
__global__ __launch_bounds__(1024) void gat_scan_coarse(int* __restrict__ data)
{
    __shared__ int tmp[1024];
    const int t = threadIdx.x;
    int v[SCAN_PER];
    int s = 0;
    #pragma unroll
    for (int j = 0; j < SCAN_PER; ++j) {
        const int i = t * SCAN_PER + j;
        v[j] = (i < SCAN_N) ? data[i] : 0;
        s += v[j];
    }
    tmp[t] = s;
    __syncthreads();
    int val = s;
    for (int st = 1; st < 1024; st <<= 1) {
        const int add = (t >= st) ? tmp[t - st] : 0;
        __syncthreads();
        val += add;
        tmp[t] = val;
        __syncthreads();
    }
    int run = val - s;
    #pragma unroll
    for (int j = 0; j < SCAN_PER; ++j) {
        const int i = t * SCAN_PER + j;
        if (i < SCAN_N) data[i] = run;
        run += v[j];
    }
}

// ---------------------------------------------------------------------------
// Coarse scatter: per-partition LDS cursors over 98 buckets (frontier 6KB
// -> L2-resident, full lines written). Entry: src | (dst&1023)<<17.
// ---------------------------------------------------------------------------
__global__ __launch_bounds__(256) void gat_scatter_coarse(
    const int* __restrict__ src, const int* __restrict__ dst,
    const int* __restrict__ cur2dA, int* __restrict__ ebufA)
{
    __shared__ int lcur[NCB];
    if (threadIdx.x < NCB)
        lcur[threadIdx.x] = cur2dA[threadIdx.x * NPART + blockIdx.x];
    __syncthreads();
    const int e0 = blockIdx.x * EPP;
    for (int e = e0 + threadIdx.x; e < e0 + EPP; e += 256) {
        const int se = src[e], de = dst[e];
        const int pos = atomicAdd(&lcur[de >> 10], 1);
        ebufA[pos] = se | ((de & (CWIN - 1)) << 17);
    }
}

// ---------------------------------------------------------------------------
// Node-sort: one 1024-thr block per coarse bucket (~16K edges). LDS 1024-bin
// histogram + scan; scatter within a 64KB window (L2-absorbed) -> true CSR
// (ebufB = src only) + nodeoff[].
// ---------------------------------------------------------------------------
__global__ __launch_bounds__(1024) void gat_nodesort(
    const int* __restrict__ ebufA, const int* __restrict__ cur2dA,
    int* __restrict__ ebufB, int* __restrict__ nodeoff)
{
    __shared__ int nh[CWIN];
    __shared__ int tmp[CWIN];
    __shared__ int cur[CWIN];

    const int t = threadIdx.x;
    const int cb = blockIdx.x;
    const int a0 = cur2dA[cb * NPART];
    const int a1 = (cb < NCB - 1) ? cur2dA[(cb + 1) * NPART] : N_EDGES;
    const int cnt = a1 - a0;

    nh[t] = 0;
    __syncthreads();

    for (int i = t; i < cnt; i += 1024)
        atomicAdd(&nh[(ebufA[a0 + i] >> 17) & (CWIN - 1)], 1);
    __syncthreads();

    // exclusive scan of nh[1024]
    const int own = nh[t];
    tmp[t] = own;
    __syncthreads();
    int val = own;
    for (int st = 1; st < 1024; st <<= 1) {
        const int add = (t >= st) ? tmp[t - st] : 0;
        __syncthreads();
        val += add;
        tmp[t] = val;
        __syncthreads();
    }
    const int excl = val - own;
    cur[t] = excl;
    const int gnode = cb * CWIN + t;
    if (gnode < N_NODES) nodeoff[gnode] = a0 + excl;
    if (cb == NCB - 1 && t == 0) nodeoff[N_NODES] = N_EDGES;
    __syncthreads();

    for (int i = t; i < cnt; i += 1024) {
        const int v = ebufA[a0 + i];
        const int pos = a0 + atomicAdd(&cur[(v >> 17) & (CWIN - 1)], 1);
        ebufB[pos] = v & 0x1FFFF;
    }
}

// ---------------------------------------------------------------------------
// CSR aggregation: wave-per-node, lane-per-edge, no LDS, no atomics.
// Chunks of 64 edges; ex/src redistributed via shfl; 4 edges per gather
// instruction (16 lanes x dwordx2 = 4 bf16 cols); float4 store by lanes 0-15.
// ---------------------------------------------------------------------------
__global__ __launch_bounds__(256) void gat_agg_csr(
    const int* __restrict__ csr, const int* __restrict__ nodeoff,
    const float* __restrict__ p_src, const float* __restrict__ p_dst,
    const unsigned short* __restrict__ Wh, float* __restrict__ out)
{
    const int t = threadIdx.x;
    const int lane = t & 63;
    const int node = __builtin_amdgcn_readfirstlane(blockIdx.x * 4 + (t >> 6));
    const int o = __builtin_amdgcn_readfirstlane(nodeoff[node]);
    const int d = __builtin_amdgcn_readfirstlane(nodeoff[node + 1]) - o;
    const float pd = p_dst[node];

    const int grp = lane >> 4;          // edge sub-slot 0..3
    const int c4 = (lane & 15) * 4;     // 4-column base

    float ssum = 0.f;
    float a0 = 0.f, a1 = 0.f, a2 = 0.f, a3 = 0.f;

    for (int kb = 0; kb < d; kb += 64) {
        const int rem = min(d - kb, 64);
        int sv_l = 0;
        float ex_l = 0.f;
        if (lane < rem) {
            sv_l = csr[o + kb + lane];
            ex_l = __expf(fmaxf(p_src[sv_l] + pd, 0.f));
        }
        float ss = ex_l;
        #pragma unroll
        for (int w = 32; w > 0; w >>= 1) ss += __shfl_xor(ss, w);
        ssum += ss;

        for (int k0 = 0; k0 < rem; k0 += 4) {
            const int kk = k0 + grp;            // 0..63, valid lane id
            const int sv = __shfl(sv_l, kk);    // lanes >= rem hold 0
            const float ex = __shfl(ex_l, kk);  // lanes >= rem hold 0.f
            const uint2 wr = *(const uint2*)(Wh + (size_t)sv * OUT_DIM + c4);
            a0 = fmaf(ex, __uint_as_float(wr.x << 16), a0);
            a1 = fmaf(ex, __uint_as_float(wr.x & 0xFFFF0000u), a1);
            a2 = fmaf(ex, __uint_as_float(wr.y << 16), a2);
            a3 = fmaf(ex, __uint_as_float(wr.y & 0xFFFF0000u), a3);
        }
    }

    a0 += __shfl_xor(a0, 16); a0 += __shfl_xor(a0, 32);
    a1 += __shfl_xor(a1, 16); a1 += __shfl_xor(a1, 32);
    a2 += __shfl_xor(a2, 16); a2 += __shfl_xor(a2, 32);
    a3 += __shfl_xor(a3, 16); a3 += __shfl_xor(a3, 32);

    if (lane < 16) {
        const float inv = (d > 0) ? 1.f / ssum : 0.f;
        float4 ov = make_float4(a0 * inv, a1 * inv, a2 * inv, a3 * inv);
        *(float4*)(out + (size_t)node * OUT_DIM + c4) = ov;
    }
}

// ---------------------------------------------------------------------------
extern "C" void kernel_launch(void* const* d_in, const int* in_sizes, int n_in,
                              void* d_out, int out_size, void* d_ws, size_t ws_size,
                              hipStream_t stream)
{
    const float* h  = (const float*)d_in[0];
    const int* src  = (const int*)d_in[1];
    const int* dst  = (const int*)d_in[2];
    const float* W  = (const float*)d_in[3];
    const float* a  = (const float*)d_in[4];
    float* out = (float*)d_out;

    // workspace layout (bytes), total ~26.9 MB; every buffer write-before-read
    char* ws = (char*)d_ws;
    unsigned short* WhB = (unsigned short*)(ws);      // 12,800,000 (bf16)
    float* p_src   = (float*)(ws + 12800000);         //    400,000
    float* p_dst   = (float*)(ws + 13200000);         //    400,000
    int*   cur2dA  = (int*)  (ws + 13600000);         //    100,352 (98*256)
    int*   nodeoff = (int*)  (ws + 13700352);         //    400,004 (N_NODES+1)
    int*   ebufA   = (int*)  (ws + 14100368);         //  6,400,000
    int*   ebufB   = (int*)  (ws + 20500368);         //  6,400,000  (end ~26.9 MB)

    gat_gemm<<<(N_NODES + 127) / 128, 256, 0, stream>>>(h, W, a, WhB, p_src, p_dst);

    gat_hist_coarse<<<NPART, 256, 0, stream>>>(dst, cur2dA);
    gat_scan_coarse<<<1, 1024, 0, stream>>>(cur2dA);
    gat_scatter_coarse<<<NPART, 256, 0, stream>>>(src, dst, cur2dA, ebufA);
    gat_nodesort<<<NCB, 1024, 0, stream>>>(ebufA, cur2dA, ebufB, nodeoff);

    gat_agg_csr<<<N_NODES / 4, 256, 0, stream>>>(ebufB, nodeoff, p_src, p_dst, WhB, out);
}

// Round 9
// 139.433 us; speedup vs baseline: 1.0277x; 1.0277x over previous
//
#include <hip/hip_runtime.h>
#include <hip/hip_bf16.h>
#include <math.h>
#include <stdint.h>

#define N_NODES 100000
#define N_EDGES 1600000
#define IN_DIM 256
#define OUT_DIM 64

#define NCB   391                        // coarse buckets: dst>>8 (391*256 >= 100000)
#define CWIN  256                        // nodes per coarse bucket
#define NPART 256                        // edge partitions; 256 * 6250 = 1.6M exact
#define EPP   (N_EDGES / NPART)          // 6250
#define SCAN_N (NCB * NPART)             // 100096
#define SCAN_BLK ((SCAN_N + 4095) / 4096) // 25

typedef __attribute__((ext_vector_type(8))) short bh8;   // 8 x bf16 frag
typedef __attribute__((ext_vector_type(4))) float f4;    // mfma accumulator

// f32 -> bf16 round-to-nearest-even
static __device__ __forceinline__ unsigned short f2bf(float f) {
    unsigned u = __float_as_uint(f);
    unsigned r = (u + 0x7FFFu + ((u >> 16) & 1u)) >> 16;
    return (unsigned short)r;
}

// ---------------------------------------------------------------------------
// Kernel A (MFMA): Wh_bf16 = bf16(h) @ bf16(W).T + fused p_src/p_dst.
// (unchanged — W resident in LDS, h global->reg, no K-loop barriers)
// ---------------------------------------------------------------------------
__global__ __launch_bounds__(256) void gat_gemm(
    const float* __restrict__ h, const float* __restrict__ W,
    const float* __restrict__ a, unsigned short* __restrict__ WhB,
    float* __restrict__ p_src, float* __restrict__ p_dst)
{
    __shared__ __align__(16) unsigned short Wlds[64 * 256];   // 32 KB

    const int t = threadIdx.x;
    const int lane = t & 63;
    const int wv = t >> 6;
    const int cl = lane & 15;
    const int g  = lane >> 4;

    {
        const int c = t >> 2;
        const int kb = (t & 3) * 8;
        #pragma unroll
        for (int it = 0; it < 8; ++it) {
            const int k16 = kb + it;
            const float4 lo = *(const float4*)(W + c * IN_DIM + k16 * 8);
            const float4 hi = *(const float4*)(W + c * IN_DIM + k16 * 8 + 4);
            unsigned short tmp[8];
            tmp[0] = f2bf(lo.x); tmp[1] = f2bf(lo.y);
            tmp[2] = f2bf(lo.z); tmp[3] = f2bf(lo.w);
            tmp[4] = f2bf(hi.x); tmp[5] = f2bf(hi.y);
            tmp[6] = f2bf(hi.z); tmp[7] = f2bf(hi.w);
            const int chunk = c * 32 + (k16 ^ (c & 7));     // XOR swizzle
            *(uint4*)&Wlds[chunk * 8] = *(uint4*)tmp;
        }
    }
    __syncthreads();

    const int node0 = blockIdx.x * 128 + wv * 32;

    float aS[4], aD[4];
    #pragma unroll
    for (int nt = 0; nt < 4; ++nt) {
        aS[nt] = a[nt * 16 + cl];
        aD[nt] = a[OUT_DIM + nt * 16 + cl];
    }

    f4 acc[2][4];
    #pragma unroll
    for (int mt = 0; mt < 2; ++mt)
        #pragma unroll
        for (int nt = 0; nt < 4; ++nt) acc[mt][nt] = (f4){0.f, 0.f, 0.f, 0.f};

    for (int ks = 0; ks < 8; ++ks) {
        bh8 bf[4];
        #pragma unroll
        for (int nt = 0; nt < 4; ++nt) {
            const int col = nt * 16 + cl;
            const int k16 = ks * 4 + g;
            const int chunk = col * 32 + (k16 ^ (col & 7));
            bf[nt] = *(const bh8*)&Wlds[chunk * 8];
        }
        #pragma unroll
        for (int mt = 0; mt < 2; ++mt) {
            int row = node0 + mt * 16 + cl;
            row = (row < N_NODES) ? row : N_NODES - 1;
            const float* hp = h + (size_t)row * IN_DIM + ks * 32 + g * 8;
            const float4 lo = *(const float4*)hp;
            const float4 hi = *(const float4*)(hp + 4);
            bh8 af;
            af[0] = (short)f2bf(lo.x); af[1] = (short)f2bf(lo.y);
            af[2] = (short)f2bf(lo.z); af[3] = (short)f2bf(lo.w);
            af[4] = (short)f2bf(hi.x); af[5] = (short)f2bf(hi.y);
            af[6] = (short)f2bf(hi.z); af[7] = (short)f2bf(hi.w);
            #pragma unroll
            for (int nt = 0; nt < 4; ++nt)
                acc[mt][nt] = __builtin_amdgcn_mfma_f32_16x16x32_bf16(
                    af, bf[nt], acc[mt][nt], 0, 0, 0);
        }
    }

    #pragma unroll
    for (int mt = 0; mt < 2; ++mt) {
        #pragma unroll
        for (int r = 0; r < 4; ++r) {
            const int row = node0 + mt * 16 + g * 4 + r;
            float ps = 0.f, pd = 0.f;
            #pragma unroll
            for (int nt = 0; nt < 4; ++nt) {
                ps = fmaf(acc[mt][nt][r], aS[nt], ps);
                pd = fmaf(acc[mt][nt][r], aD[nt], pd);
            }
            #pragma unroll
            for (int o = 8; o > 0; o >>= 1) {
                ps += __shfl_xor(ps, o);
                pd += __shfl_xor(pd, o);
            }
            if (row < N_NODES) {
                #pragma unroll
                for (int nt = 0; nt < 4; ++nt)
                    WhB[(size_t)row * OUT_DIM + nt * 16 + cl] =
                        f2bf(acc[mt][nt][r]);
                if (cl == 0) { p_src[row] = ps; p_dst[row] = pd; }
            }
        }
    }
}

// ---------------------------------------------------------------------------
// Coarse histogram: cnt[coarse_bucket][partition], LDS-combined.
// ---------------------------------------------------------------------------
__global__ __launch_bounds__(256) void gat_hist_coarse(
    const int* __restrict__ dst, int* __restrict__ cur2dA)
{
    __shared__ int lh[NCB];
    for (int i = threadIdx.x; i < NCB; i += 256) lh[i] = 0;
    __syncthreads();
    const int e0 = blockIdx.x * EPP;
    for (int e = e0 + threadIdx.x; e < e0 + EPP; e += 256)
        atomicAdd(&lh[dst[e] >> 8], 1);
    __syncthreads();
    for (int i = threadIdx.x; i < NCB; i += 256)
        cur2dA[i * NPART + blockIdx.x] = lh[i];
}

// ---------------------------------------------------------------------------
// 3-phase exclusive scan over cur2dA[100096], in place.
// ---------------------------------------------------------------------------
__global__ __launch_bounds__(1024) void gat_scan1(int* __restrict__ data,
                                                  int* __restrict__ bsum)
{
    __shared__ int ts[1024];
    const int base = blockIdx.x * 4096 + threadIdx.x * 4;
    int v[4];
    #pragma unroll
    for (int j = 0; j < 4; ++j) {
        const int i = base + j;
        v[j] = (i < SCAN_N) ? data[i] : 0;
    }
    const int tsum = v[0] + v[1] + v[2] + v[3];
    ts[threadIdx.x] = tsum;
    __syncthreads();
    int val = tsum;
    for (int s = 1; s < 1024; s <<= 1) {
        const int add = (threadIdx.x >= s) ? ts[threadIdx.x - s] : 0;
        __syncthreads();
        val += add;
        ts[threadIdx.x] = val;
        __syncthreads();
    }
    int run = val - tsum;
    #pragma unroll
    for (int j = 0; j < 4; ++j) {
        const int i = base + j;
        if (i < SCAN_N) data[i] = run;
        run += v[j];
    }
    if (threadIdx.x == 1023) bsum[blockIdx.x] = val;
}

__global__ __launch_bounds__(256) void gat_scan2(int* __restrict__ bsum)
{
    __shared__ int tmp[256];
    const int t = threadIdx.x;
    const int v = (t < SCAN_BLK) ? bsum[t] : 0;
    tmp[t] = v;
    __syncthreads();
    int val = v;
    for (int s = 1; s < 256; s <<= 1) {
        const int add = (t >= s) ? tmp[t - s] : 0;
        __syncthreads();
        val += add;
        tmp[t] = val;
        __syncthreads();
    }
    if (t < SCAN_BLK) bsum[t] = val - v;
}

__global__ __launch_bounds__(1024) void gat_scan3(int* __restrict__ data,
                                                  const int* __restrict__ bsum)
{
    const int add = bsum[blockIdx.x];
    const int base = blockIdx.x * 4096 + threadIdx.x * 4;
    #pragma unroll
    for (int j = 0; j < 4; ++j) {
        const int i = base + j;
        if (i < SCAN_N) data[i] += add;
    }
}

// ---------------------------------------------------------------------------
// Coarse scatter: per-partition LDS cursors over 391 buckets (frontier
// ~25KB -> L2-resident). Entry: src | (dst&255)<<17.
// ---------------------------------------------------------------------------
__global__ __launch_bounds__(256) void gat_scatter_coarse(
    const int* __restrict__ src, const int* __restrict__ dst,
    const int* __restrict__ cur2dA, int* __restrict__ ebufA)
{
    __shared__ int lcur[NCB];
    for (int i = threadIdx.x; i < NCB; i += 256)
        lcur[i] = cur2dA[i * NPART + blockIdx.x];
    __syncthreads();
    const int e0 = blockIdx.x * EPP;
    for (int e = e0 + threadIdx.x; e < e0 + EPP; e += 256) {
        const int se = src[e], de = dst[e];
        const int pos = atomicAdd(&lcur[de >> 8], 1);
        ebufA[pos] = se | ((de & (CWIN - 1)) << 17);
    }
}

// ---------------------------------------------------------------------------
// Node-sort: one 256-thr block per coarse bucket (~4100 edges). 256-bin LDS
// histogram + wave-shfl scan (no barrier rounds); scatter within a 16KB
// window (L2-absorbed) -> true CSR (ebufB = src only) + nodeoff[].
// ---------------------------------------------------------------------------
__global__ __launch_bounds__(256) void gat_nodesort(
    const int* __restrict__ ebufA, const int* __restrict__ cur2dA,
    int* __restrict__ ebufB, int* __restrict__ nodeoff)
{
    __shared__ int nh[CWIN];
    __shared__ int cur[CWIN];
    __shared__ int wsum[4];

    const int t = threadIdx.x;
    const int cb = blockIdx.x;
    const int a0 = cur2dA[cb * NPART];
    const int a1 = (cb < NCB - 1) ? cur2dA[(cb + 1) * NPART] : N_EDGES;
    const int cnt = a1 - a0;

    nh[t] = 0;
    __syncthreads();

    for (int i = t; i < cnt; i += 256)
        atomicAdd(&nh[(ebufA[a0 + i] >> 17) & (CWIN - 1)], 1);
    __syncthreads();

    // exclusive scan of nh[256]: per-wave shfl scan + 4-wave combine
    const int own = nh[t];
    const int lane = t & 63;
    int val = own;
    #pragma unroll
    for (int s = 1; s < 64; s <<= 1) {
        const int n = __shfl_up(val, s);
        if (lane >= s) val += n;
    }
    if (lane == 63) wsum[t >> 6] = val;
    __syncthreads();
    int wadd = 0;
    #pragma unroll
    for (int w = 0; w < 4; ++w) wadd += (w < (t >> 6)) ? wsum[w] : 0;
    const int excl = val - own + wadd;
    cur[t] = excl;
    const int gnode = cb * CWIN + t;
    if (gnode < N_NODES) nodeoff[gnode] = a0 + excl;
    if (cb == NCB - 1 && t == 0) nodeoff[N_NODES] = N_EDGES;
    __syncthreads();

    for (int i = t; i < cnt; i += 256) {
        const int v = ebufA[a0 + i];
        const int pos = a0 + atomicAdd(&cur[(v >> 17) & (CWIN - 1)], 1);
        ebufB[pos] = v & 0x1FFFF;
    }
}

// ---------------------------------------------------------------------------
// CSR aggregation v3: wave-per-node, single pass, NO cross-lane ops in the
// loop. 16-lane group g handles edge k0+g: csr/p_src reads are group-uniform
// (broadcast fetch), exp computed redundantly (VALU idle), Wh row gathered
// coalesced (16 lanes x dwordx2 = 128B). Group partials combined with
// 2 shfl_xor at the end (group-uniform values -> exact).
// ---------------------------------------------------------------------------
__global__ __launch_bounds__(256) void gat_agg_csr(
    const int* __restrict__ csr, const int* __restrict__ nodeoff,
    const float* __restrict__ p_src, const float* __restrict__ p_dst,
    const unsigned short* __restrict__ Wh, float* __restrict__ out)
{
    const int t = threadIdx.x;
    const int lane = t & 63;
    const int node = __builtin_amdgcn_readfirstlane(blockIdx.x * 4 + (t >> 6));
    const int o = __builtin_amdgcn_readfirstlane(nodeoff[node]);
    const int d = __builtin_amdgcn_readfirstlane(nodeoff[node + 1]) - o;
    const float pd = p_dst[node];

    const int grp = lane >> 4;          // edge sub-slot 0..3
    const int c4 = (lane & 15) * 4;     // 4-column base

    float ssum = 0.f;
    float a0 = 0.f, a1 = 0.f, a2 = 0.f, a3 = 0.f;

    #pragma unroll 2
    for (int k0 = 0; k0 < d; k0 += 4) {
        const int kk = k0 + grp;
        if (kk < d) {
            const int sv = csr[o + kk];
            const float ex = __expf(fmaxf(p_src[sv] + pd, 0.f));
            const uint2 wr = *(const uint2*)(Wh + (size_t)sv * OUT_DIM + c4);
            ssum += ex;
            a0 = fmaf(ex, __uint_as_float(wr.x << 16), a0);
            a1 = fmaf(ex, __uint_as_float(wr.x & 0xFFFF0000u), a1);
            a2 = fmaf(ex, __uint_as_float(wr.y << 16), a2);
            a3 = fmaf(ex, __uint_as_float(wr.y & 0xFFFF0000u), a3);
        }
    }

    ssum += __shfl_xor(ssum, 16); ssum += __shfl_xor(ssum, 32);
    a0 += __shfl_xor(a0, 16); a0 += __shfl_xor(a0, 32);
    a1 += __shfl_xor(a1, 16); a1 += __shfl_xor(a1, 32);
    a2 += __shfl_xor(a2, 16); a2 += __shfl_xor(a2, 32);
    a3 += __shfl_xor(a3, 16); a3 += __shfl_xor(a3, 32);

    if (lane < 16) {
        const float inv = (d > 0) ? 1.f / ssum : 0.f;
        float4 ov = make_float4(a0 * inv, a1 * inv, a2 * inv, a3 * inv);
        *(float4*)(out + (size_t)node * OUT_DIM + c4) = ov;
    }
}

// ---------------------------------------------------------------------------
extern "C" void kernel_launch(void* const* d_in, const int* in_sizes, int n_in,
                              void* d_out, int out_size, void* d_ws, size_t ws_size,
                              hipStream_t stream)
{
    const float* h  = (const float*)d_in[0];
    const int* src  = (const int*)d_in[1];
    const int* dst  = (const int*)d_in[2];
    const float* W  = (const float*)d_in[3];
    const float* a  = (const float*)d_in[4];
    float* out = (float*)d_out;

    // workspace layout (bytes), total ~27.2 MB; every buffer write-before-read
    char* ws = (char*)d_ws;
    unsigned short* WhB = (unsigned short*)(ws);      // 12,800,000 (bf16)
    float* p_src   = (float*)(ws + 12800000);         //    400,000
    float* p_dst   = (float*)(ws + 13200000);         //    400,000
    int*   cur2dA  = (int*)  (ws + 13600000);         //    400,384 (391*256)
    int*   bsum    = (int*)  (ws + 14000384);         //        400
    int*   nodeoff = (int*)  (ws + 14000784);         //    400,004
    int*   ebufA   = (int*)  (ws + 14400800);         //  6,400,000
    int*   ebufB   = (int*)  (ws + 20800800);         //  6,400,000  (end ~27.2 MB)

    gat_gemm<<<(N_NODES + 127) / 128, 256, 0, stream>>>(h, W, a, WhB, p_src, p_dst);

    gat_hist_coarse<<<NPART, 256, 0, stream>>>(dst, cur2dA);
    gat_scan1<<<SCAN_BLK, 1024, 0, stream>>>(cur2dA, bsum);
    gat_scan2<<<1, 256, 0, stream>>>(bsum);
    gat_scan3<<<SCAN_BLK, 1024, 0, stream>>>(cur2dA, bsum);
    gat_scatter_coarse<<<NPART, 256, 0, stream>>>(src, dst, cur2dA, ebufA);
    gat_nodesort<<<NCB, 256, 0, stream>>>(ebufA, cur2dA, ebufB, nodeoff);

    gat_agg_csr<<<N_NODES / 4, 256, 0, stream>>>(ebufB, nodeoff, p_src, p_dst, WhB, out);
}